// Round 8
// baseline (3137.020 us; speedup 1.0000x reference)
//
#include <hip/hip_runtime.h>

#define D 32
#define RBC 4096          // rows per coarse bucket (12-bit local row)
#define RBC_SHIFT 12
#define CAP 32            // staged entries per bucket per block
#define MAXNC 512         // max coarse buckets (N2 <= 2M)

// ---------------------------------------------------------------------------
__global__ __launch_bounds__(256) void zero_i32(int* __restrict__ p, int n) {
    int i = blockIdx.x * blockDim.x + threadIdx.x;
    int stride = gridDim.x * blockDim.x;
    for (; i < n; i += stride) p[i] = 0;
}

// ---------------------------------------------------------------------------
// coarse-bucket histogram of entries (2 per edge), LDS-binned
// ---------------------------------------------------------------------------
__global__ __launch_bounds__(256) void bucket_hist(
        const int* __restrict__ src, const int* __restrict__ dst,
        int* __restrict__ bcnt, int NU, int E) {
    __shared__ int h[MAXNC];
    for (int i = threadIdx.x; i < MAXNC; i += 256) h[i] = 0;
    __syncthreads();
    int i = blockIdx.x * 256 + threadIdx.x;
    int stride = gridDim.x * 256;
    for (; i < E; i += stride) {
        int s = src[i];
        int d = dst[i];
        atomicAdd(&h[s >> RBC_SHIFT], 1);
        atomicAdd(&h[(NU + d) >> RBC_SHIFT], 1);
    }
    __syncthreads();
    for (int j = threadIdx.x; j < MAXNC; j += 256)
        if (h[j]) atomicAdd(&bcnt[j], h[j]);
}

// ---------------------------------------------------------------------------
// one-block scan over <=512 bucket counts producing BOTH:
//   boffsA/gcur: 16-entry-ALIGNED ents windows (for full-line staged flushes)
//   coffs:       EXACT csr windows (gapless global CSR)
// ---------------------------------------------------------------------------
__global__ __launch_bounds__(MAXNC) void scan_buckets(
        const int* __restrict__ bcnt, int* __restrict__ boffsA,
        int* __restrict__ gcur, int* __restrict__ coffs, int nbk) {
    __shared__ int sa[MAXNC], se[MAXNC];
    int t = threadIdx.x;
    int c = (t < nbk) ? bcnt[t] : 0;
    int a = (c + 15) & ~15;
    sa[t] = a;
    se[t] = c;
    __syncthreads();
    for (int off = 1; off < MAXNC; off <<= 1) {
        int va = (t >= off) ? sa[t - off] : 0;
        int ve = (t >= off) ? se[t - off] : 0;
        __syncthreads();
        sa[t] += va;
        se[t] += ve;
        __syncthreads();
    }
    int pa = (t == 0) ? 0 : sa[t - 1];
    int pe = (t == 0) ? 0 : se[t - 1];
    if (t < nbk) {
        boffsA[t] = pa;
        gcur[t]   = pa;
        coffs[t]  = pe;
        if (t == nbk - 1) {
            boffsA[nbk] = sa[t];
            coffs[nbk]  = se[t];
        }
    }
}

// ---------------------------------------------------------------------------
// LDS line-staged multisplit partition (full 64B aligned line flushes)
// ---------------------------------------------------------------------------
__global__ __launch_bounds__(512) void partition(
        const int* __restrict__ src, const int* __restrict__ dst,
        int* __restrict__ gcur, unsigned int* __restrict__ ents,
        int NU, int E, int nbk) {
    __shared__ unsigned int stage[MAXNC * CAP];   // 64 KB
    __shared__ int lcnt[MAXNC];
    int t = threadIdx.x;
    lcnt[t] = 0;
    __syncthreads();

    long per = ((long)E + gridDim.x - 1) / gridDim.x;
    long i0 = (long)blockIdx.x * per;
    long i1 = i0 + per;
    if (i1 > E) i1 = E;
    int nrounds = (i1 > i0) ? (int)((i1 - i0 + 511) >> 9) : 0;

    long i = i0 + t;
    int cs = 0, cd = 0;
    bool cv = (nrounds > 0) && (i < i1);
    if (cv) { cs = src[i]; cd = dst[i]; }

    for (int r = 0; r < nrounds; ++r) {
        long nx = i + 512;
        int ns = 0, nd = 0;
        bool nv = (nx < i1);
        if (nv) { ns = src[nx]; nd = dst[nx]; }   // prefetch next round

        if (cv) {
            int c1 = cs >> RBC_SHIFT;
            unsigned e1 = ((unsigned)(cs & (RBC - 1)) << 20) | (unsigned)cd;
            int p1 = atomicAdd(&lcnt[c1], 1);
            if (p1 < CAP) stage[(c1 << 5) + p1] = e1;
            else ents[atomicAdd(&gcur[c1], 1)] = e1;   // rare overflow
            int r2 = NU + cd;
            int c2 = r2 >> RBC_SHIFT;
            unsigned e2 = ((unsigned)(r2 & (RBC - 1)) << 20) | (unsigned)cs;
            int p2 = atomicAdd(&lcnt[c2], 1);
            if (p2 < CAP) stage[(c2 << 5) + p2] = e2;
            else ents[atomicAdd(&gcur[c2], 1)] = e2;
        }
        __syncthreads();

        if (t < nbk) {
            int cnt = lcnt[t];
            if (cnt > CAP) cnt = CAP;
            int nf = (cnt >= 16) ? (cnt & ~15) : 0;
            if (nf) {
                int g = atomicAdd(&gcur[t], nf);   // stays 16-aligned
#pragma unroll
                for (int k = 0; k < CAP; k += 4) {
                    if (k < nf) {
                        uint4 w = *(uint4*)&stage[(t << 5) + k];
                        *(uint4*)&ents[g + k] = w;
                    }
                }
                for (int k = 0; k < cnt - nf; ++k)
                    stage[(t << 5) + k] = stage[(t << 5) + nf + k];
            }
            lcnt[t] = cnt - nf;
        }
        __syncthreads();
        cs = ns; cd = nd; cv = nv; i = nx;
    }

    if (t < nbk) {
        int cnt = lcnt[t];
        if (cnt > CAP) cnt = CAP;
        if (cnt > 0) {
            int g = atomicAdd(&gcur[t], cnt);
            for (int k = 0; k < cnt; ++k) ents[g + k] = stage[(t << 5) + k];
        }
    }
}

// ---------------------------------------------------------------------------
// block-local counting sort: one block per coarse bucket (4096 rows).
// Reads its ents window, emits gapless global CSR + exact per-row offs.
// ---------------------------------------------------------------------------
__global__ __launch_bounds__(512) void local_sort(
        const unsigned int* __restrict__ ents, const int* __restrict__ boffsA,
        const int* __restrict__ bcnt, const int* __restrict__ coffs,
        int* __restrict__ csr, int* __restrict__ offs, long N2, int nbk) {
    __shared__ int cnt[RBC];
    __shared__ int cur[RBC];
    __shared__ int tsum[512];
    int b = blockIdx.x, t = threadIdx.x;
    int e0 = boffsA[b];
    int n  = bcnt[b];
    int c0 = coffs[b];

    for (int j = t; j < RBC; j += 512) cnt[j] = 0;
    __syncthreads();
    for (int k = t; k < n; k += 512)
        atomicAdd(&cnt[ents[e0 + k] >> 20], 1);
    __syncthreads();

    int x[8], pre[8], sum = 0;
#pragma unroll
    for (int j = 0; j < 8; ++j) {
        x[j] = cnt[t * 8 + j];
        pre[j] = sum;
        sum += x[j];
    }
    tsum[t] = sum;
    __syncthreads();
    for (int off = 1; off < 512; off <<= 1) {
        int v = (t >= off) ? tsum[t - off] : 0;
        __syncthreads();
        tsum[t] += v;
        __syncthreads();
    }
    int p = (t == 0) ? 0 : tsum[t - 1];
    long rowbase = (long)b << RBC_SHIFT;
#pragma unroll
    for (int j = 0; j < 8; ++j) {
        int o = p + pre[j];
        cur[t * 8 + j] = o;
        long row = rowbase + t * 8 + j;
        if (row < N2) offs[row] = c0 + o;
    }
    if (b == nbk - 1 && t == 0) offs[N2] = c0 + n;
    __syncthreads();

    for (int k = t; k < n; k += 512) {
        unsigned en = ents[e0 + k];
        int rl = (int)(en >> 20);
        int pos = atomicAdd(&cur[rl], 1);
        csr[c0 + pos] = (int)(en & 0xFFFFFu);
    }
}

// ---------------------------------------------------------------------------
// one phase of fused aggregate + SAGE transform. One 32-lane group per row.
// Neighbor rows gathered as float4 per 8-lane octet (one full 128B line per
// request, 4 rows per instruction), predicated tails (no duplicate loads).
// Quad partial sums reduced via shfl_xor butterfly, redistributed to scalar
// lane layout, then mean + self@Wself + mean@Wneigh + b.
// ---------------------------------------------------------------------------
__global__ __launch_bounds__(256, 8) void sage_phase(
        const float* __restrict__ self_embed,
        const float* __restrict__ nbr_embed,
        const int* __restrict__ offs,      // [N+1], pre-offset for this phase
        const int* __restrict__ csr,
        const float* __restrict__ Wself, const float* __restrict__ Wneigh,
        const float* __restrict__ bias,
        float* __restrict__ out, int N) {
    __shared__ float sWs[D * D];
    __shared__ float sWn[D * D];
    __shared__ float sb[D];
    for (int i = threadIdx.x; i < D * D; i += blockDim.x) {
        sWs[i] = Wself[i];
        sWn[i] = Wneigh[i];
    }
    if (threadIdx.x < D) sb[threadIdx.x] = bias[threadIdx.x];
    __syncthreads();

    int lane = threadIdx.x & 31;
    int q  = lane & 7;        // 16B quad within a row
    int rs = lane >> 3;       // row slot 0..3
    long g  = ((long)blockIdx.x * blockDim.x + threadIdx.x) >> 5;
    long ng = ((long)gridDim.x * blockDim.x) >> 5;

    for (long row = g; row < N; row += ng) {
        int o0 = offs[row];
        int o1 = offs[row + 1];
        int deg = o1 - o0;
        float4 a4 = make_float4(0.f, 0.f, 0.f, 0.f);

        for (int j0 = o0; j0 < o1; j0 += 32) {
            int nb = o1 - j0;
            if (nb > 32) nb = 32;
            // batch-load up to 32 neighbor indices (one coalesced line)
            int idx = csr[j0 + (lane < nb ? lane : nb - 1)];
            for (int cc = 0; cc < nb; cc += 16) {
                float4 v[4];
#pragma unroll
                for (int c = 0; c < 4; ++c) {
                    int slot = cc + c * 4 + rs;
                    int bi = __shfl(idx, slot < nb ? slot : nb - 1, 32);
                    v[c] = make_float4(0.f, 0.f, 0.f, 0.f);
                    if (slot < nb)
                        v[c] = *(const float4*)(nbr_embed + (long)bi * D + q * 4);
                }
#pragma unroll
                for (int c = 0; c < 4; ++c) {
                    a4.x += v[c].x; a4.y += v[c].y;
                    a4.z += v[c].z; a4.w += v[c].w;
                }
            }
        }

        // butterfly-sum over the 4 row slots (flip bits 3 and 4 of lane)
        a4.x += __shfl_xor(a4.x, 8);  a4.y += __shfl_xor(a4.y, 8);
        a4.z += __shfl_xor(a4.z, 8);  a4.w += __shfl_xor(a4.w, 8);
        a4.x += __shfl_xor(a4.x, 16); a4.y += __shfl_xor(a4.y, 16);
        a4.z += __shfl_xor(a4.z, 16); a4.w += __shfl_xor(a4.w, 16);

        // redistribute: lane wants element `lane` = quad (lane>>2), comp (lane&3)
        int qt = lane >> 2;
        int ct = lane & 3;
        float m0 = __shfl(a4.x, qt, 32);
        float m1 = __shfl(a4.y, qt, 32);
        float m2 = __shfl(a4.z, qt, 32);
        float m3 = __shfl(a4.w, qt, 32);
        float mm = (ct == 0) ? m0 : (ct == 1) ? m1 : (ct == 2) ? m2 : m3;
        float m = mm / fmaxf((float)deg, 1.0f);

        float e = self_embed[row * D + lane];
        float acc = sb[lane];
#pragma unroll
        for (int k = 0; k < D; ++k) {
            acc += __shfl(e, k, 32) * sWs[k * D + lane]
                 + __shfl(m, k, 32) * sWn[k * D + lane];
        }
        out[row * D + lane] = acc;
    }
}

// ---------------------------------------------------------------------------
extern "C" void kernel_launch(void* const* d_in, const int* in_sizes, int n_in,
                              void* d_out, int out_size, void* d_ws, size_t ws_size,
                              hipStream_t stream) {
    const float* user_embed = (const float*)d_in[0];
    const float* item_embed = (const float*)d_in[1];
    const float* W_self     = (const float*)d_in[2];
    const float* W_neigh    = (const float*)d_in[3];
    const float* bias       = (const float*)d_in[4];
    const int*   edge_src   = (const int*)d_in[5];
    const int*   edge_dst   = (const int*)d_in[6];

    const int NU = in_sizes[0] / D;
    const int NI = in_sizes[1] / D;
    const int E  = in_sizes[5];
    const long N2 = (long)NU + NI;
    const int nbk = (int)((N2 + RBC - 1) >> RBC_SHIFT);   // 489 for 2M rows

    float* user_out = (float*)d_out;            // [NU*D]
    float* item_out = user_out + (long)NU * D;  // [NI*D]

    // workspace (int units):
    // offs[N2+1] | bcnt[nbk] | boffsA[nbk+1] | gcur[nbk] | coffs[nbk+1] |
    // ents[2E + 15*nbk] | csr[2E]
    long p = 0;
    int* offs   = (int*)d_ws + p;  p += N2 + 1;   p = (p + 3) & ~3L;
    int* bcnt   = (int*)d_ws + p;  p += nbk;
    int* boffsA = (int*)d_ws + p;  p += nbk + 1;
    int* gcur   = (int*)d_ws + p;  p += nbk;
    int* coffs  = (int*)d_ws + p;  p += nbk + 1;  p = (p + 3) & ~3L;
    unsigned int* ents = (unsigned int*)((int*)d_ws + p);
    p += 2L * E + 15L * nbk;       p = (p + 3) & ~3L;
    int* csr    = (int*)d_ws + p;

    // ---- build combined CSR ----
    zero_i32<<<2, 256, 0, stream>>>(bcnt, nbk);
    bucket_hist<<<512, 256, 0, stream>>>(edge_src, edge_dst, bcnt, NU, E);
    scan_buckets<<<1, MAXNC, 0, stream>>>(bcnt, boffsA, gcur, coffs, nbk);
    partition<<<512, 512, 0, stream>>>(edge_src, edge_dst, gcur, ents, NU, E, nbk);
    local_sort<<<nbk, 512, 0, stream>>>(ents, boffsA, bcnt, coffs, csr, offs,
                                        N2, nbk);

    // ---- fused gather-mean + SAGE transform, phase-split for L3 residency ----
    sage_phase<<<2048, 256, 0, stream>>>(user_embed, item_embed, offs, csr,
                                         W_self, W_neigh, bias, user_out, NU);
    sage_phase<<<2048, 256, 0, stream>>>(item_embed, user_embed, offs + NU, csr,
                                         W_self, W_neigh, bias, item_out, NI);
}

// Round 9
// 2941.286 us; speedup vs baseline: 1.0665x; 1.0665x over previous
//
#include <hip/hip_runtime.h>

#define D 32
#define RBC 4096          // rows per coarse bucket (12-bit local row)
#define RBC_SHIFT 12
#define CAP 32            // staged entries per bucket per block
#define MAXNC 512         // max coarse buckets (N2 <= 2M)

// ---------------------------------------------------------------------------
__global__ __launch_bounds__(256) void zero_i32(int* __restrict__ p, int n) {
    int i = blockIdx.x * blockDim.x + threadIdx.x;
    int stride = gridDim.x * blockDim.x;
    for (; i < n; i += stride) p[i] = 0;
}

// ---------------------------------------------------------------------------
// f32 -> bf16 (round-to-nearest-even), float4 in / ushort4 out
// ---------------------------------------------------------------------------
static __device__ __forceinline__ unsigned short f2bf(float f) {
    unsigned u = __float_as_uint(f);
    u += 0x7FFFu + ((u >> 16) & 1u);
    return (unsigned short)(u >> 16);
}

__global__ __launch_bounds__(256) void to_bf16(
        const float* __restrict__ in, unsigned short* __restrict__ out, long n4) {
    long i = (long)blockIdx.x * 256 + threadIdx.x;
    long stride = (long)gridDim.x * 256;
    for (; i < n4; i += stride) {
        float4 v = ((const float4*)in)[i];
        ushort4 o;
        o.x = f2bf(v.x); o.y = f2bf(v.y); o.z = f2bf(v.z); o.w = f2bf(v.w);
        ((ushort4*)out)[i] = o;
    }
}

// ---------------------------------------------------------------------------
// coarse-bucket histogram of entries (2 per edge), LDS-binned
// ---------------------------------------------------------------------------
__global__ __launch_bounds__(256) void bucket_hist(
        const int* __restrict__ src, const int* __restrict__ dst,
        int* __restrict__ bcnt, int NU, int E) {
    __shared__ int h[MAXNC];
    for (int i = threadIdx.x; i < MAXNC; i += 256) h[i] = 0;
    __syncthreads();
    int i = blockIdx.x * 256 + threadIdx.x;
    int stride = gridDim.x * 256;
    for (; i < E; i += stride) {
        int s = src[i];
        int d = dst[i];
        atomicAdd(&h[s >> RBC_SHIFT], 1);
        atomicAdd(&h[(NU + d) >> RBC_SHIFT], 1);
    }
    __syncthreads();
    for (int j = threadIdx.x; j < MAXNC; j += 256)
        if (h[j]) atomicAdd(&bcnt[j], h[j]);
}

// ---------------------------------------------------------------------------
// one-block scan over <=512 bucket counts producing BOTH:
//   boffsA/gcur: 16-entry-ALIGNED ents windows (for full-line staged flushes)
//   coffs:       EXACT csr windows (gapless global CSR)
// ---------------------------------------------------------------------------
__global__ __launch_bounds__(MAXNC) void scan_buckets(
        const int* __restrict__ bcnt, int* __restrict__ boffsA,
        int* __restrict__ gcur, int* __restrict__ coffs, int nbk) {
    __shared__ int sa[MAXNC], se[MAXNC];
    int t = threadIdx.x;
    int c = (t < nbk) ? bcnt[t] : 0;
    int a = (c + 15) & ~15;
    sa[t] = a;
    se[t] = c;
    __syncthreads();
    for (int off = 1; off < MAXNC; off <<= 1) {
        int va = (t >= off) ? sa[t - off] : 0;
        int ve = (t >= off) ? se[t - off] : 0;
        __syncthreads();
        sa[t] += va;
        se[t] += ve;
        __syncthreads();
    }
    int pa = (t == 0) ? 0 : sa[t - 1];
    int pe = (t == 0) ? 0 : se[t - 1];
    if (t < nbk) {
        boffsA[t] = pa;
        gcur[t]   = pa;
        coffs[t]  = pe;
        if (t == nbk - 1) {
            boffsA[nbk] = sa[t];
            coffs[nbk]  = se[t];
        }
    }
}

// ---------------------------------------------------------------------------
// LDS line-staged multisplit partition (full 64B aligned line flushes)
// ---------------------------------------------------------------------------
__global__ __launch_bounds__(512) void partition(
        const int* __restrict__ src, const int* __restrict__ dst,
        int* __restrict__ gcur, unsigned int* __restrict__ ents,
        int NU, int E, int nbk) {
    __shared__ unsigned int stage[MAXNC * CAP];   // 64 KB
    __shared__ int lcnt[MAXNC];
    int t = threadIdx.x;
    lcnt[t] = 0;
    __syncthreads();

    long per = ((long)E + gridDim.x - 1) / gridDim.x;
    long i0 = (long)blockIdx.x * per;
    long i1 = i0 + per;
    if (i1 > E) i1 = E;
    int nrounds = (i1 > i0) ? (int)((i1 - i0 + 511) >> 9) : 0;

    long i = i0 + t;
    int cs = 0, cd = 0;
    bool cv = (nrounds > 0) && (i < i1);
    if (cv) { cs = src[i]; cd = dst[i]; }

    for (int r = 0; r < nrounds; ++r) {
        long nx = i + 512;
        int ns = 0, nd = 0;
        bool nv = (nx < i1);
        if (nv) { ns = src[nx]; nd = dst[nx]; }   // prefetch next round

        if (cv) {
            int c1 = cs >> RBC_SHIFT;
            unsigned e1 = ((unsigned)(cs & (RBC - 1)) << 20) | (unsigned)cd;
            int p1 = atomicAdd(&lcnt[c1], 1);
            if (p1 < CAP) stage[(c1 << 5) + p1] = e1;
            else ents[atomicAdd(&gcur[c1], 1)] = e1;   // rare overflow
            int r2 = NU + cd;
            int c2 = r2 >> RBC_SHIFT;
            unsigned e2 = ((unsigned)(r2 & (RBC - 1)) << 20) | (unsigned)cs;
            int p2 = atomicAdd(&lcnt[c2], 1);
            if (p2 < CAP) stage[(c2 << 5) + p2] = e2;
            else ents[atomicAdd(&gcur[c2], 1)] = e2;
        }
        __syncthreads();

        if (t < nbk) {
            int cnt = lcnt[t];
            if (cnt > CAP) cnt = CAP;
            int nf = (cnt >= 16) ? (cnt & ~15) : 0;
            if (nf) {
                int g = atomicAdd(&gcur[t], nf);   // stays 16-aligned
#pragma unroll
                for (int k = 0; k < CAP; k += 4) {
                    if (k < nf) {
                        uint4 w = *(uint4*)&stage[(t << 5) + k];
                        *(uint4*)&ents[g + k] = w;
                    }
                }
                for (int k = 0; k < cnt - nf; ++k)
                    stage[(t << 5) + k] = stage[(t << 5) + nf + k];
            }
            lcnt[t] = cnt - nf;
        }
        __syncthreads();
        cs = ns; cd = nd; cv = nv; i = nx;
    }

    if (t < nbk) {
        int cnt = lcnt[t];
        if (cnt > CAP) cnt = CAP;
        if (cnt > 0) {
            int g = atomicAdd(&gcur[t], cnt);
            for (int k = 0; k < cnt; ++k) ents[g + k] = stage[(t << 5) + k];
        }
    }
}

// ---------------------------------------------------------------------------
// block-local counting sort: one block per coarse bucket (4096 rows).
// Reads its ents window, emits gapless global CSR + exact per-row offs.
// ---------------------------------------------------------------------------
__global__ __launch_bounds__(512) void local_sort(
        const unsigned int* __restrict__ ents, const int* __restrict__ boffsA,
        const int* __restrict__ bcnt, const int* __restrict__ coffs,
        int* __restrict__ csr, int* __restrict__ offs, long N2, int nbk) {
    __shared__ int cnt[RBC];
    __shared__ int cur[RBC];
    __shared__ int tsum[512];
    int b = blockIdx.x, t = threadIdx.x;
    int e0 = boffsA[b];
    int n  = bcnt[b];
    int c0 = coffs[b];

    for (int j = t; j < RBC; j += 512) cnt[j] = 0;
    __syncthreads();
    for (int k = t; k < n; k += 512)
        atomicAdd(&cnt[ents[e0 + k] >> 20], 1);
    __syncthreads();

    int x[8], pre[8], sum = 0;
#pragma unroll
    for (int j = 0; j < 8; ++j) {
        x[j] = cnt[t * 8 + j];
        pre[j] = sum;
        sum += x[j];
    }
    tsum[t] = sum;
    __syncthreads();
    for (int off = 1; off < 512; off <<= 1) {
        int v = (t >= off) ? tsum[t - off] : 0;
        __syncthreads();
        tsum[t] += v;
        __syncthreads();
    }
    int p = (t == 0) ? 0 : tsum[t - 1];
    long rowbase = (long)b << RBC_SHIFT;
#pragma unroll
    for (int j = 0; j < 8; ++j) {
        int o = p + pre[j];
        cur[t * 8 + j] = o;
        long row = rowbase + t * 8 + j;
        if (row < N2) offs[row] = c0 + o;
    }
    if (b == nbk - 1 && t == 0) offs[N2] = c0 + n;
    __syncthreads();

    for (int k = t; k < n; k += 512) {
        unsigned en = ents[e0 + k];
        int rl = (int)(en >> 20);
        int pos = atomicAdd(&cur[rl], 1);
        csr[c0 + pos] = (int)(en & 0xFFFFFu);
    }
}

// ---------------------------------------------------------------------------
// one phase of fused aggregate + SAGE transform. One 32-lane group per row.
// Neighbor table is bf16 (64B rows) gathered as uint (ushort2) per lane:
// 16 consecutive lanes read 16 consecutive dwords of one row (the only
// pattern the coalescer rewards), 2 rows per 32-lane group per instruction,
// 8 loads in flight (16 row-slots per inner iter). Predicated tails.
// Halves combined with shfl_xor(16); 2-shuffle redistribution to scalar
// lane layout; f32 accumulate; mean + self@Wself + mean@Wneigh + b.
// ---------------------------------------------------------------------------
__global__ __launch_bounds__(256, 8) void sage_phase(
        const float* __restrict__ self_embed,
        const unsigned short* __restrict__ nbr16,   // bf16 rows, 32 elems each
        const int* __restrict__ offs,      // [N+1], pre-offset for this phase
        const int* __restrict__ csr,
        const float* __restrict__ Wself, const float* __restrict__ Wneigh,
        const float* __restrict__ bias,
        float* __restrict__ out, int N) {
    __shared__ float sWs[D * D];
    __shared__ float sWn[D * D];
    __shared__ float sb[D];
    for (int i = threadIdx.x; i < D * D; i += blockDim.x) {
        sWs[i] = Wself[i];
        sWn[i] = Wneigh[i];
    }
    if (threadIdx.x < D) sb[threadIdx.x] = bias[threadIdx.x];
    __syncthreads();

    int lane = threadIdx.x & 31;
    int half = lane >> 4;       // which of 2 rows this lane serves
    int el   = lane & 15;       // dword (ushort2) index within the 64B row
    long g  = ((long)blockIdx.x * blockDim.x + threadIdx.x) >> 5;
    long ng = ((long)gridDim.x * blockDim.x) >> 5;

    for (long row = g; row < N; row += ng) {
        int o0 = offs[row];
        int o1 = offs[row + 1];
        int deg = o1 - o0;
        float s0 = 0.f, s1 = 0.f;   // partial sums for elements 2*el, 2*el+1

        for (int j0 = o0; j0 < o1; j0 += 32) {
            int nb = o1 - j0;
            if (nb > 32) nb = 32;
            // batch-load up to 32 neighbor indices (one coalesced line)
            int idx = csr[j0 + (lane < nb ? lane : nb - 1)];
            for (int k = 0; k < nb; k += 16) {
                unsigned uv[8];
#pragma unroll
                for (int u = 0; u < 8; ++u) {
                    int slot = k + 2 * u + half;
                    int bi = __shfl(idx, slot < nb ? slot : nb - 1, 32);
                    uv[u] = 0u;
                    if (slot < nb)
                        uv[u] = *(const unsigned*)(nbr16 + (long)bi * D + el * 2);
                }
#pragma unroll
                for (int u = 0; u < 8; ++u) {
                    s0 += __uint_as_float(uv[u] << 16);          // elem 2*el
                    s1 += __uint_as_float(uv[u] & 0xFFFF0000u);  // elem 2*el+1
                }
            }
        }

        // combine the two half-slot partial sums (lane <-> lane^16)
        s0 += __shfl_xor(s0, 16);
        s1 += __shfl_xor(s1, 16);

        // redistribute: lane wants element `lane` = (el= lane>>1, comp= lane&1)
        float mx = __shfl(s0, lane >> 1, 32);
        float my = __shfl(s1, lane >> 1, 32);
        float mm = (lane & 1) ? my : mx;
        float m = mm / fmaxf((float)deg, 1.0f);

        float e = self_embed[row * D + lane];
        float acc = sb[lane];
#pragma unroll
        for (int k = 0; k < D; ++k) {
            acc += __shfl(e, k, 32) * sWs[k * D + lane]
                 + __shfl(m, k, 32) * sWn[k * D + lane];
        }
        out[row * D + lane] = acc;
    }
}

// ---------------------------------------------------------------------------
extern "C" void kernel_launch(void* const* d_in, const int* in_sizes, int n_in,
                              void* d_out, int out_size, void* d_ws, size_t ws_size,
                              hipStream_t stream) {
    const float* user_embed = (const float*)d_in[0];
    const float* item_embed = (const float*)d_in[1];
    const float* W_self     = (const float*)d_in[2];
    const float* W_neigh    = (const float*)d_in[3];
    const float* bias       = (const float*)d_in[4];
    const int*   edge_src   = (const int*)d_in[5];
    const int*   edge_dst   = (const int*)d_in[6];

    const int NU = in_sizes[0] / D;
    const int NI = in_sizes[1] / D;
    const int E  = in_sizes[5];
    const long N2 = (long)NU + NI;
    const int nbk = (int)((N2 + RBC - 1) >> RBC_SHIFT);   // 489 for 2M rows

    float* user_out = (float*)d_out;            // [NU*D]
    float* item_out = user_out + (long)NU * D;  // [NI*D]

    // workspace (int units):
    // offs[N2+1] | bcnt[nbk] | boffsA[nbk+1] | gcur[nbk] | coffs[nbk+1] |
    // csr[2E] | R: shared region = max(ents[2E+15nbk]*4B, max(NU,NI)*64B)
    //   R holds ents during the build, then the bf16 gather table (item for
    //   phase 1, user for phase 2) — ents is dead after local_sort.
    long p = 0;
    int* offs   = (int*)d_ws + p;  p += N2 + 1;   p = (p + 3) & ~3L;
    int* bcnt   = (int*)d_ws + p;  p += nbk;
    int* boffsA = (int*)d_ws + p;  p += nbk + 1;
    int* gcur   = (int*)d_ws + p;  p += nbk;
    int* coffs  = (int*)d_ws + p;  p += nbk + 1;  p = (p + 3) & ~3L;
    int* csr    = (int*)d_ws + p;  p += 2L * E;   p = (p + 3) & ~3L;
    unsigned int*   ents = (unsigned int*)((int*)d_ws + p);
    unsigned short* bf16 = (unsigned short*)ents;

    // ---- build combined CSR ----
    zero_i32<<<2, 256, 0, stream>>>(bcnt, nbk);
    bucket_hist<<<512, 256, 0, stream>>>(edge_src, edge_dst, bcnt, NU, E);
    scan_buckets<<<1, MAXNC, 0, stream>>>(bcnt, boffsA, gcur, coffs, nbk);
    partition<<<512, 512, 0, stream>>>(edge_src, edge_dst, gcur, ents, NU, E, nbk);
    local_sort<<<nbk, 512, 0, stream>>>(ents, boffsA, bcnt, coffs, csr, offs,
                                        N2, nbk);

    // ---- user phase: gather from bf16 item table (overwrites ents) ----
    to_bf16<<<2048, 256, 0, stream>>>(item_embed, bf16, (long)NI * D / 4);
    sage_phase<<<2048, 256, 0, stream>>>(user_embed, bf16, offs, csr,
                                         W_self, W_neigh, bias, user_out, NU);

    // ---- item phase: gather from bf16 user table (same region) ----
    to_bf16<<<2048, 256, 0, stream>>>(user_embed, bf16, (long)NU * D / 4);
    sage_phase<<<2048, 256, 0, stream>>>(item_embed, bf16, offs + NU, csr,
                                         W_self, W_neigh, bias, item_out, NI);
}

// Round 10
// 1655.836 us; speedup vs baseline: 1.8945x; 1.7763x over previous
//
#include <hip/hip_runtime.h>

#define D 32
#define RBC 4096          // rows per coarse bucket (12-bit local row)
#define RBC_SHIFT 12
#define CAP 32            // staged entries per bucket per block
#define MAXNC 512         // max coarse buckets (N2 <= 2M)

// ---------------------------------------------------------------------------
__global__ __launch_bounds__(256) void zero_i32(int* __restrict__ p, int n) {
    int i = blockIdx.x * blockDim.x + threadIdx.x;
    int stride = gridDim.x * blockDim.x;
    for (; i < n; i += stride) p[i] = 0;
}

// ---------------------------------------------------------------------------
// coarse-bucket histogram of entries (2 per edge), LDS-binned
// ---------------------------------------------------------------------------
__global__ __launch_bounds__(256) void bucket_hist(
        const int* __restrict__ src, const int* __restrict__ dst,
        int* __restrict__ bcnt, int NU, int E) {
    __shared__ int h[MAXNC];
    for (int i = threadIdx.x; i < MAXNC; i += 256) h[i] = 0;
    __syncthreads();
    int i = blockIdx.x * 256 + threadIdx.x;
    int stride = gridDim.x * 256;
    for (; i < E; i += stride) {
        int s = src[i];
        int d = dst[i];
        atomicAdd(&h[s >> RBC_SHIFT], 1);
        atomicAdd(&h[(NU + d) >> RBC_SHIFT], 1);
    }
    __syncthreads();
    for (int j = threadIdx.x; j < MAXNC; j += 256)
        if (h[j]) atomicAdd(&bcnt[j], h[j]);
}

// ---------------------------------------------------------------------------
// one-block scan over <=512 bucket counts producing BOTH:
//   boffsA/gcur: 16-entry-ALIGNED ents windows (for full-line staged flushes)
//   coffs:       EXACT csr windows (gapless global CSR)
// ---------------------------------------------------------------------------
__global__ __launch_bounds__(MAXNC) void scan_buckets(
        const int* __restrict__ bcnt, int* __restrict__ boffsA,
        int* __restrict__ gcur, int* __restrict__ coffs, int nbk) {
    __shared__ int sa[MAXNC], se[MAXNC];
    int t = threadIdx.x;
    int c = (t < nbk) ? bcnt[t] : 0;
    int a = (c + 15) & ~15;
    sa[t] = a;
    se[t] = c;
    __syncthreads();
    for (int off = 1; off < MAXNC; off <<= 1) {
        int va = (t >= off) ? sa[t - off] : 0;
        int ve = (t >= off) ? se[t - off] : 0;
        __syncthreads();
        sa[t] += va;
        se[t] += ve;
        __syncthreads();
    }
    int pa = (t == 0) ? 0 : sa[t - 1];
    int pe = (t == 0) ? 0 : se[t - 1];
    if (t < nbk) {
        boffsA[t] = pa;
        gcur[t]   = pa;
        coffs[t]  = pe;
        if (t == nbk - 1) {
            boffsA[nbk] = sa[t];
            coffs[nbk]  = se[t];
        }
    }
}

// ---------------------------------------------------------------------------
// LDS line-staged multisplit partition (full 64B aligned line flushes)
// ---------------------------------------------------------------------------
__global__ __launch_bounds__(512) void partition(
        const int* __restrict__ src, const int* __restrict__ dst,
        int* __restrict__ gcur, unsigned int* __restrict__ ents,
        int NU, int E, int nbk) {
    __shared__ unsigned int stage[MAXNC * CAP];   // 64 KB
    __shared__ int lcnt[MAXNC];
    int t = threadIdx.x;
    lcnt[t] = 0;
    __syncthreads();

    long per = ((long)E + gridDim.x - 1) / gridDim.x;
    long i0 = (long)blockIdx.x * per;
    long i1 = i0 + per;
    if (i1 > E) i1 = E;
    int nrounds = (i1 > i0) ? (int)((i1 - i0 + 511) >> 9) : 0;

    long i = i0 + t;
    int cs = 0, cd = 0;
    bool cv = (nrounds > 0) && (i < i1);
    if (cv) { cs = src[i]; cd = dst[i]; }

    for (int r = 0; r < nrounds; ++r) {
        long nx = i + 512;
        int ns = 0, nd = 0;
        bool nv = (nx < i1);
        if (nv) { ns = src[nx]; nd = dst[nx]; }   // prefetch next round

        if (cv) {
            int c1 = cs >> RBC_SHIFT;
            unsigned e1 = ((unsigned)(cs & (RBC - 1)) << 20) | (unsigned)cd;
            int p1 = atomicAdd(&lcnt[c1], 1);
            if (p1 < CAP) stage[(c1 << 5) + p1] = e1;
            else ents[atomicAdd(&gcur[c1], 1)] = e1;   // rare overflow
            int r2 = NU + cd;
            int c2 = r2 >> RBC_SHIFT;
            unsigned e2 = ((unsigned)(r2 & (RBC - 1)) << 20) | (unsigned)cs;
            int p2 = atomicAdd(&lcnt[c2], 1);
            if (p2 < CAP) stage[(c2 << 5) + p2] = e2;
            else ents[atomicAdd(&gcur[c2], 1)] = e2;
        }
        __syncthreads();

        if (t < nbk) {
            int cnt = lcnt[t];
            if (cnt > CAP) cnt = CAP;
            int nf = (cnt >= 16) ? (cnt & ~15) : 0;
            if (nf) {
                int g = atomicAdd(&gcur[t], nf);   // stays 16-aligned
#pragma unroll
                for (int k = 0; k < CAP; k += 4) {
                    if (k < nf) {
                        uint4 w = *(uint4*)&stage[(t << 5) + k];
                        *(uint4*)&ents[g + k] = w;
                    }
                }
                for (int k = 0; k < cnt - nf; ++k)
                    stage[(t << 5) + k] = stage[(t << 5) + nf + k];
            }
            lcnt[t] = cnt - nf;
        }
        __syncthreads();
        cs = ns; cd = nd; cv = nv; i = nx;
    }

    if (t < nbk) {
        int cnt = lcnt[t];
        if (cnt > CAP) cnt = CAP;
        if (cnt > 0) {
            int g = atomicAdd(&gcur[t], cnt);
            for (int k = 0; k < cnt; ++k) ents[g + k] = stage[(t << 5) + k];
        }
    }
}

// ---------------------------------------------------------------------------
// block-local counting sort: one block per coarse bucket (4096 rows).
// Reads its ents window, emits gapless global CSR + exact per-row offs.
// ---------------------------------------------------------------------------
__global__ __launch_bounds__(512) void local_sort(
        const unsigned int* __restrict__ ents, const int* __restrict__ boffsA,
        const int* __restrict__ bcnt, const int* __restrict__ coffs,
        int* __restrict__ csr, int* __restrict__ offs, long N2, int nbk) {
    __shared__ int cnt[RBC];
    __shared__ int cur[RBC];
    __shared__ int tsum[512];
    int b = blockIdx.x, t = threadIdx.x;
    int e0 = boffsA[b];
    int n  = bcnt[b];
    int c0 = coffs[b];

    for (int j = t; j < RBC; j += 512) cnt[j] = 0;
    __syncthreads();
    for (int k = t; k < n; k += 512)
        atomicAdd(&cnt[ents[e0 + k] >> 20], 1);
    __syncthreads();

    int x[8], pre[8], sum = 0;
#pragma unroll
    for (int j = 0; j < 8; ++j) {
        x[j] = cnt[t * 8 + j];
        pre[j] = sum;
        sum += x[j];
    }
    tsum[t] = sum;
    __syncthreads();
    for (int off = 1; off < 512; off <<= 1) {
        int v = (t >= off) ? tsum[t - off] : 0;
        __syncthreads();
        tsum[t] += v;
        __syncthreads();
    }
    int p = (t == 0) ? 0 : tsum[t - 1];
    long rowbase = (long)b << RBC_SHIFT;
#pragma unroll
    for (int j = 0; j < 8; ++j) {
        int o = p + pre[j];
        cur[t * 8 + j] = o;
        long row = rowbase + t * 8 + j;
        if (row < N2) offs[row] = c0 + o;
    }
    if (b == nbk - 1 && t == 0) offs[N2] = c0 + n;
    __syncthreads();

    for (int k = t; k < n; k += 512) {
        unsigned en = ents[e0 + k];
        int rl = (int)(en >> 20);
        int pos = atomicAdd(&cur[rl], 1);
        csr[c0 + pos] = (int)(en & 0xFFFFFu);
    }
}

// ---------------------------------------------------------------------------
// one phase of fused aggregate + SAGE transform (dst rows gather from one
// source table, which stays L3-resident for the whole dispatch).
// One 32-lane group per row; batched index loads; 8-deep independent gathers
// of full 128B f32 rows (lane-consecutive-dword — the coalescer's pattern).
// ---------------------------------------------------------------------------
__global__ __launch_bounds__(256, 8) void sage_phase(
        const float* __restrict__ self_embed,
        const float* __restrict__ nbr_embed,
        const int* __restrict__ offs,      // [N+1], pre-offset for this phase
        const int* __restrict__ csr,
        const float* __restrict__ Wself, const float* __restrict__ Wneigh,
        const float* __restrict__ bias,
        float* __restrict__ out, int N) {
    __shared__ float sWs[D * D];
    __shared__ float sWn[D * D];
    __shared__ float sb[D];
    for (int i = threadIdx.x; i < D * D; i += blockDim.x) {
        sWs[i] = Wself[i];
        sWn[i] = Wneigh[i];
    }
    if (threadIdx.x < D) sb[threadIdx.x] = bias[threadIdx.x];
    __syncthreads();

    int lane = threadIdx.x & 31;
    long g  = ((long)blockIdx.x * blockDim.x + threadIdx.x) >> 5;
    long ng = ((long)gridDim.x * blockDim.x) >> 5;

    for (long row = g; row < N; row += ng) {
        int o0 = offs[row];
        int o1 = offs[row + 1];
        int deg = o1 - o0;
        float s = 0.f;
        for (int j0 = o0; j0 < o1; j0 += 32) {
            int nb = o1 - j0;
            if (nb > 32) nb = 32;
            int idx = csr[j0 + (lane < nb ? lane : nb - 1)];
            for (int k = 0; k < nb; k += 8) {
                int kr = nb - k;  // >= 1
                float v[8];
#pragma unroll
                for (int u = 0; u < 8; ++u) {
                    int uu = u < kr ? u : kr - 1;   // clamp (dup loads cache-hit)
                    int bi = __shfl(idx, k + uu, 32);
                    v[u] = nbr_embed[(long)bi * D + lane];
                }
#pragma unroll
                for (int u = 0; u < 8; ++u) {
                    s += (u < kr) ? v[u] : 0.f;
                }
            }
        }
        float m = s / fmaxf((float)deg, 1.0f);
        float e = self_embed[row * D + lane];
        float acc = sb[lane];
#pragma unroll
        for (int k = 0; k < D; ++k) {
            acc += __shfl(e, k, 32) * sWs[k * D + lane]
                 + __shfl(m, k, 32) * sWn[k * D + lane];
        }
        out[row * D + lane] = acc;
    }
}

// ---------------------------------------------------------------------------
extern "C" void kernel_launch(void* const* d_in, const int* in_sizes, int n_in,
                              void* d_out, int out_size, void* d_ws, size_t ws_size,
                              hipStream_t stream) {
    const float* user_embed = (const float*)d_in[0];
    const float* item_embed = (const float*)d_in[1];
    const float* W_self     = (const float*)d_in[2];
    const float* W_neigh    = (const float*)d_in[3];
    const float* bias       = (const float*)d_in[4];
    const int*   edge_src   = (const int*)d_in[5];
    const int*   edge_dst   = (const int*)d_in[6];

    const int NU = in_sizes[0] / D;
    const int NI = in_sizes[1] / D;
    const int E  = in_sizes[5];
    const long N2 = (long)NU + NI;
    const int nbk = (int)((N2 + RBC - 1) >> RBC_SHIFT);   // 489 for 2M rows

    float* user_out = (float*)d_out;            // [NU*D]
    float* item_out = user_out + (long)NU * D;  // [NI*D]

    // workspace (int units):
    // offs[N2+1] | bcnt[nbk] | boffsA[nbk+1] | gcur[nbk] | coffs[nbk+1] |
    // ents[2E + 15*nbk] | csr[2E]
    long p = 0;
    int* offs   = (int*)d_ws + p;  p += N2 + 1;   p = (p + 3) & ~3L;
    int* bcnt   = (int*)d_ws + p;  p += nbk;
    int* boffsA = (int*)d_ws + p;  p += nbk + 1;
    int* gcur   = (int*)d_ws + p;  p += nbk;
    int* coffs  = (int*)d_ws + p;  p += nbk + 1;  p = (p + 3) & ~3L;
    unsigned int* ents = (unsigned int*)((int*)d_ws + p);
    p += 2L * E + 15L * nbk;       p = (p + 3) & ~3L;
    int* csr    = (int*)d_ws + p;

    // ---- build combined CSR ----
    zero_i32<<<2, 256, 0, stream>>>(bcnt, nbk);
    bucket_hist<<<512, 256, 0, stream>>>(edge_src, edge_dst, bcnt, NU, E);
    scan_buckets<<<1, MAXNC, 0, stream>>>(bcnt, boffsA, gcur, coffs, nbk);
    partition<<<512, 512, 0, stream>>>(edge_src, edge_dst, gcur, ents, NU, E, nbk);
    local_sort<<<nbk, 512, 0, stream>>>(ents, boffsA, bcnt, coffs, csr, offs,
                                        N2, nbk);

    // ---- fused gather-mean + SAGE transform, phase-split for L3 residency ----
    sage_phase<<<2048, 256, 0, stream>>>(user_embed, item_embed, offs, csr,
                                         W_self, W_neigh, bias, user_out, NU);
    sage_phase<<<2048, 256, 0, stream>>>(item_embed, user_embed, offs + NU, csr,
                                         W_self, W_neigh, bias, item_out, NI);
}